// Round 17
// baseline (128.818 us; speedup 1.0000x reference)
//
#include <hip/hip_runtime.h>

// LIF spiking net forward, v17 — 3-digit i8 MFMA GEMM, 2-buffer LDS,
// 3 blocks/CU (12 waves = 3/SIMD).
//   W -> 3 signed base-256 digits of round(W * 2^26)  (|top digit| <= ~97)
//   S (binary fp32) -> i8
//   I = sum_d 2^(8d) * (S_i8 @ digit_d^T)  in int64, one fp32 round.
//   (v15/v16 proved this numerics path: absmax 0.0)
// v17: v15(8w) and v16(2x4w) both ran 2 waves/SIMD -- co-residency added no
//   waves. 2 LDS buffers (40960B/block) -> 3 blocks/CU = 3 waves/SIMD (VGPR
//   cap 170 >= ~155 used). Per-tile vmcnt(0) drain is covered by the other
//   two blocks' compute.

#define N_IN   1024
#define N_OUT  512
#define DECAY_F 0.95122942450071400910f
#define SCALE     67108864.0               // 2^26
#define SCALE_INV 1.4901161193847656e-08f  // 2^-26

typedef int  v4i  __attribute__((ext_vector_type(4)));
typedef int  v16i __attribute__((ext_vector_type(16)));

typedef __attribute__((address_space(1))) const void gv_t;
typedef __attribute__((address_space(3))) void lv_t;
__device__ __forceinline__ void gl16(const signed char* g, signed char* l) {
    __builtin_amdgcn_global_load_lds((gv_t*)g, (lv_t*)l, 16, 0, 0);
}

// ---------------- kernel 1: fused prep: S->i8  |  W->3 digit planes --------
__global__ __launch_bounds__(256) void prep(const float* __restrict__ S,
                                            signed char* __restrict__ S8,
                                            const float* __restrict__ W,
                                            signed char* __restrict__ D8,
                                            int nS16blocks) {
    if ((int)blockIdx.x < nS16blocks) {
        const int g = blockIdx.x * 256 + threadIdx.x;
        const float4* p = reinterpret_cast<const float4*>(S) + (size_t)g * 4;
        union { signed char c[16]; int4 v; } u;
#pragma unroll
        for (int q = 0; q < 4; ++q) {
            const float4 v = p[q];
            u.c[q * 4 + 0] = (signed char)(v.x != 0.f);
            u.c[q * 4 + 1] = (signed char)(v.y != 0.f);
            u.c[q * 4 + 2] = (signed char)(v.z != 0.f);
            u.c[q * 4 + 3] = (signed char)(v.w != 0.f);
        }
        reinterpret_cast<int4*>(S8)[g] = u.v;
    } else {
        const int n  = blockIdx.x - nS16blocks;   // 0..511
        const int k0 = threadIdx.x * 4;
        const float4 wv = *reinterpret_cast<const float4*>(W + (size_t)n * N_IN + k0);
        const float ww[4] = {wv.x, wv.y, wv.z, wv.w};
        int pk[3] = {0, 0, 0};
#pragma unroll
        for (int j = 0; j < 4; ++j) {
            long long wi = (long long)rint((double)ww[j] * SCALE);
            const int d0 = (int)((wi + 128) & 255) - 128; wi = (wi - d0) >> 8;
            const int d1 = (int)((wi + 128) & 255) - 128; wi = (wi - d1) >> 8;
            const int d2 = (int)wi;           // |d2| <= ~97
            pk[0] |= (d0 & 255) << (8 * j);
            pk[1] |= (d1 & 255) << (8 * j);
            pk[2] |= (d2 & 255) << (8 * j);
        }
#pragma unroll
        for (int d = 0; d < 3; ++d)
            *reinterpret_cast<int*>(D8 + (size_t)(d * N_OUT + n) * N_IN + k0) = pk[d];
    }
}

// ---------------- kernel 2: i8 MFMA GEMM, BM=128, 2-buf, 3 blocks/CU -------
#define BM 128
#define BN 64
#define BK 64
#define ATILE (BM * BK)            // 8192 B
#define BTILE (192 * BK)           // 12288 B (3 digits x 64 rows)
#define BUFSZ (ATILE + BTILE)      // 20480 B; 2 buffers = 40960 B

#define BARRIER __builtin_amdgcn_s_barrier()
#define SB0 __builtin_amdgcn_sched_barrier(0)
#define LGKM(n) do { asm volatile("s_waitcnt lgkmcnt(" #n ")" ::: "memory"); SB0; } while (0)
#define VMCNT_(n) asm volatile("s_waitcnt vmcnt(" #n ")" ::: "memory")
#define LDV(off) (*reinterpret_cast<const v4i*>(lds + (off)))
#define MFMA_I8 __builtin_amdgcn_mfma_i32_32x32x32_i8

__global__ __launch_bounds__(256, 3) void gemm_i8(
        const signed char* __restrict__ S8,   // (M, 1024)
        const signed char* __restrict__ D8,   // (1536, 1024), row = d*512+n
        float* __restrict__ I, int M) {       // (M, 512)
    extern __shared__ signed char lds[];

    const int tid  = threadIdx.x;
    const int lane = tid & 63;
    const int w    = tid >> 6;          // 0..3
    const int wwm  = w >> 1;            // 0..1 -> M offset *64
    const int wwn  = w & 1;             // 0..1 -> N offset *32

    // XCD-aware bijective swizzle (grid 2000 = 8*250)
    const int nwx = (M / BM) * (N_OUT / BN) / 8;  // 250
    const int u   = (blockIdx.x & 7) * nwx + (blockIdx.x >> 3);
    const int bm  = u >> 3;
    const int bn  = u & 7;
    const int m0 = bm * BM;
    const int n0 = bn * BN;

    // staging geometry: linear LDS [row][64], source column pre-swizzled so
    // reads use col ^ ((row>>1)&3)<<4. Per tile: 5 gl16/wave (A x2, B x3).
    const int lrow  = lane >> 2;             // 0..15
    const int sslot = (lane & 3) << 4;
    const int swzs  = ((lrow >> 1) & 3) << 4;
    const int scola = sslot ^ swzs;
    const int srw   = w * 16 + lrow;         // 0..63

    const signed char* aSrc0 = S8 + (size_t)(m0 + srw) * N_IN + scola;
    const signed char* aSrc1 = aSrc0 + (size_t)64 * N_IN;
    // B digit plane d: LDS rows d*64 + j ; global row d*512 + n0 + j
    const signed char* bS0 = D8 + (size_t)(0 * N_OUT + n0 + srw) * N_IN + scola;
    const signed char* bS1 = D8 + (size_t)(1 * N_OUT + n0 + srw) * N_IN + scola;
    const signed char* bS2 = D8 + (size_t)(2 * N_OUT + n0 + srw) * N_IN + scola;

    const int aD0 = (w * 16) * 64;
    const int aD1 = aD0 + 64 * 64;
    const int bD0 = ATILE + (0 * 64 + w * 16) * 64;
    const int bD1 = ATILE + (1 * 64 + w * 16) * 64;
    const int bD2 = ATILE + (2 * 64 + w * 16) * 64;

    v16i acc[2][3];
#pragma unroll
    for (int mf = 0; mf < 2; ++mf)
#pragma unroll
        for (int d = 0; d < 3; ++d)
#pragma unroll
            for (int i = 0; i < 16; ++i) acc[mf][d][i] = 0;

    const int fr = lane & 31;
    const int kh = (lane >> 5) * 16;
    const int swzr = ((fr >> 1) & 3) << 4;
    const int kx0 = kh ^ swzr;                // ksub0 byte offset (swizzled)
    const int kx1 = (32 + kh) ^ swzr;         // ksub1
    const int ra0 = (wwm * 64 + fr) * 64;
    const int ra1 = (wwm * 64 + 32 + fr) * 64;
    const int rb0 = ATILE + (0 * 64 + wwn * 32 + fr) * 64;
    const int rb1 = ATILE + (1 * 64 + wwn * 32 + fr) * 64;
    const int rb2 = ATILE + (2 * 64 + wwn * 32 + fr) * 64;

#define STAGE(STG, KT) do {                                                       \
        gl16(aSrc0 + (KT) * BK, lds + (STG) * BUFSZ + aD0);                       \
        gl16(aSrc1 + (KT) * BK, lds + (STG) * BUFSZ + aD1);                       \
        gl16(bS0 + (KT) * BK, lds + (STG) * BUFSZ + bD0);                         \
        gl16(bS1 + (KT) * BK, lds + (STG) * BUFSZ + bD1);                         \
        gl16(bS2 + (KT) * BK, lds + (STG) * BUFSZ + bD2);                         \
    } while (0)

// one K-tile: X/Y pipelined fragment reads, next-tile staging issued early,
// counted lgkmcnt; vmcnt(0) drain + raw barrier at tile end (drain covered
// by the 2 co-resident blocks).
#define TILE_STEP(CUR, KT, DOSTAGE)                                               \
    {                                                                             \
        const int base = (CUR) * BUFSZ;                                           \
        const int stg  = ((CUR) ^ 1);                                             \
        v4i xa0, xa1, xb0, xb1, xb2;                                              \
        v4i ya0, ya1, yb0, yb1, yb2;                                              \
        xa0 = LDV(base + ra0 + kx0);                                              \
        xa1 = LDV(base + ra1 + kx0);                                              \
        xb0 = LDV(base + rb0 + kx0);                                              \
        xb1 = LDV(base + rb1 + kx0);                                              \
        xb2 = LDV(base + rb2 + kx0);                                              \
        SB0;                                                                      \
        if (DOSTAGE) STAGE(stg, KT + 1);                                          \
        ya0 = LDV(base + ra0 + kx1);                                              \
        ya1 = LDV(base + ra1 + kx1);                                              \
        yb0 = LDV(base + rb0 + kx1);                                              \
        yb1 = LDV(base + rb1 + kx1);                                              \
        yb2 = LDV(base + rb2 + kx1);                                              \
        SB0;                                                                      \
        LGKM(5);                                                                  \
        __builtin_amdgcn_s_setprio(1);                                            \
        acc[0][0] = MFMA_I8(xa0, xb0, acc[0][0], 0, 0, 0);                        \
        acc[1][0] = MFMA_I8(xa1, xb0, acc[1][0], 0, 0, 0);                        \
        acc[0][1] = MFMA_I8(xa0, xb1, acc[0][1], 0, 0, 0);                        \
        acc[1][1] = MFMA_I8(xa1, xb1, acc[1][1], 0, 0, 0);                        \
        acc[0][2] = MFMA_I8(xa0, xb2, acc[0][2], 0, 0, 0);                        \
        acc[1][2] = MFMA_I8(xa1, xb2, acc[1][2], 0, 0, 0);                        \
        __builtin_amdgcn_s_setprio(0);                                            \
        LGKM(0);                                                                  \
        __builtin_amdgcn_s_setprio(1);                                            \
        acc[0][0] = MFMA_I8(ya0, yb0, acc[0][0], 0, 0, 0);                        \
        acc[1][0] = MFMA_I8(ya1, yb0, acc[1][0], 0, 0, 0);                        \
        acc[0][1] = MFMA_I8(ya0, yb1, acc[0][1], 0, 0, 0);                        \
        acc[1][1] = MFMA_I8(ya1, yb1, acc[1][1], 0, 0, 0);                        \
        acc[0][2] = MFMA_I8(ya0, yb2, acc[0][2], 0, 0, 0);                        \
        acc[1][2] = MFMA_I8(ya1, yb2, acc[1][2], 0, 0, 0);                        \
        __builtin_amdgcn_s_setprio(0);                                            \
        VMCNT_(0);                                                                \
        BARRIER;                                                                  \
    }

    // prologue: tile0 staged into buf0
    STAGE(0, 0);
    VMCNT_(0);
    BARRIER;

    TILE_STEP(0, 0,  1)
    TILE_STEP(1, 1,  1)
    TILE_STEP(0, 2,  1)
    TILE_STEP(1, 3,  1)
    TILE_STEP(0, 4,  1)
    TILE_STEP(1, 5,  1)
    TILE_STEP(0, 6,  1)
    TILE_STEP(1, 7,  1)
    TILE_STEP(0, 8,  1)
    TILE_STEP(1, 9,  1)
    TILE_STEP(0, 10, 1)
    TILE_STEP(1, 11, 1)
    TILE_STEP(0, 12, 1)
    TILE_STEP(1, 13, 1)
    TILE_STEP(0, 14, 1)
    TILE_STEP(1, 15, 0)

    // epilogue: combine 3 digits in int64, one fp32 rounding
    const int col = fr;
    const int rb_ = (lane >> 5) * 4;
#pragma unroll
    for (int mf = 0; mf < 2; ++mf) {
#pragma unroll
        for (int reg = 0; reg < 16; ++reg) {
            const int row = (reg & 3) + 8 * (reg >> 2) + rb_;
            const long long v =
                ((long long)acc[mf][2][reg] << 16) +
                ((long long)acc[mf][1][reg] << 8) + (long long)acc[mf][0][reg];
            I[(size_t)(m0 + wwm * 64 + mf * 32 + row) * N_OUT + n0 + wwn * 32 + col] =
                (float)v * SCALE_INV;
        }
    }
}
#undef STAGE
#undef TILE_STEP

// ---------------- kernel 3: LIF scan, 1 wave/CU, deep prefetch ----------------
#define UT 50
__global__ __launch_bounds__(64) void lif_scan3(float* __restrict__ IO, int T) {
    const int idx = blockIdx.x * 64 + threadIdx.x;   // chain id, 16384 total
    const int b = idx >> 9, o = idx & (N_OUT - 1);
    float* p = IO + (size_t)b * T * N_OUT + o;
    float ca[UT], cb[UT];
    float v = 0.f;
#pragma unroll
    for (int j = 0; j < UT; ++j) ca[j] = p[(size_t)j * N_OUT];
#pragma unroll 1
    for (int t0 = 0; t0 < T; t0 += 2 * UT) {
        if (t0 + UT < T) {
#pragma unroll
            for (int j = 0; j < UT; ++j) cb[j] = p[(size_t)(t0 + UT + j) * N_OUT];
        }
#pragma unroll
        for (int j = 0; j < UT; ++j) {
            v = v * DECAY_F + ca[j];
            float s = (v > 1.0f) ? 1.0f : 0.f;
            v *= (1.f - s);
            ca[j] = s;
        }
#pragma unroll
        for (int j = 0; j < UT; ++j) p[(size_t)(t0 + j) * N_OUT] = ca[j];
        if (t0 + UT >= T) break;
        if (t0 + 2 * UT < T) {
#pragma unroll
            for (int j = 0; j < UT; ++j) ca[j] = p[(size_t)(t0 + 2 * UT + j) * N_OUT];
        }
#pragma unroll
        for (int j = 0; j < UT; ++j) {
            v = v * DECAY_F + cb[j];
            float s = (v > 1.0f) ? 1.0f : 0.f;
            v *= (1.f - s);
            cb[j] = s;
        }
#pragma unroll
        for (int j = 0; j < UT; ++j) p[(size_t)(t0 + UT + j) * N_OUT] = cb[j];
    }
}

// ---------------- fallback: v3 gather path ----------------
__global__ __launch_bounds__(256) void transpose_w(const float* __restrict__ W,
                                                   float* __restrict__ WT) {
    __shared__ float t[32][33];
    const int k0 = blockIdx.x * 32;
    const int n0 = blockIdx.y * 32;
    const int lx = threadIdx.x & 31;
    const int ly = threadIdx.x >> 5;
#pragma unroll
    for (int r = ly; r < 32; r += 8)
        t[r][lx] = W[(size_t)(n0 + r) * N_IN + k0 + lx];
    __syncthreads();
#pragma unroll
    for (int r = ly; r < 32; r += 8)
        WT[(size_t)(k0 + r) * N_OUT + n0 + lx] = t[lx][r];
}

__global__ __launch_bounds__(256) void gather_rows(
        const float* __restrict__ S, const float* __restrict__ WT,
        float* __restrict__ I, int M) {
    const int wid  = blockIdx.x * 4 + (threadIdx.x >> 6);
    const int lane = threadIdx.x & 63;
    if (wid >= M) return;
    const float* srow = S + (size_t)wid * N_IN;
    float4 a0 = {0.f, 0.f, 0.f, 0.f};
    float4 a1 = {0.f, 0.f, 0.f, 0.f};
    float sv[16];
#pragma unroll
    for (int g = 0; g < 16; ++g) sv[g] = srow[g * 64 + lane];
#pragma unroll
    for (int g = 0; g < 16; ++g) {
        unsigned long long m = __ballot(sv[g] != 0.0f);
        while (m) {
            const int bb = __builtin_ctzll(m);
            m &= m - 1;
            const int k = g * 64 + bb;
            const float* wp = WT + (size_t)k * N_OUT + lane * 4;
            const float4 w0 = *reinterpret_cast<const float4*>(wp);
            const float4 w1 = *reinterpret_cast<const float4*>(wp + 256);
            a0.x += w0.x; a0.y += w0.y; a0.z += w0.z; a0.w += w0.w;
            a1.x += w1.x; a1.y += w1.y; a1.z += w1.z; a1.w += w1.w;
        }
    }
    float* op = I + (size_t)wid * N_OUT + lane * 4;
    *reinterpret_cast<float4*>(op) = a0;
    *reinterpret_cast<float4*>(op + 256) = a1;
}

extern "C" void kernel_launch(void* const* d_in, const int* in_sizes, int n_in,
                              void* d_out, int out_size, void* d_ws, size_t ws_size,
                              hipStream_t stream) {
    const float* S = (const float*)d_in[0];   // (B, T, n_in) binary spikes, fp32
    const float* W = (const float*)d_in[1];   // (n_out, n_in), fp32
    float* out = (float*)d_out;               // (B, T, n_out), fp32

    const int K = N_IN;
    const int M = in_sizes[0] / K;            // 32000
    const int B = 32;
    const int T = M / B;                      // 1000

    const size_t s8_bytes = (size_t)M * N_IN;                 // 32.77 MB
    const size_t d8_bytes = (size_t)3 * N_OUT * N_IN;         // 1.5 MB
    const size_t need = s8_bytes + d8_bytes;

    if (ws_size >= need && (M % BM) == 0 && ((M / BM) * (N_OUT / BN)) % 8 == 0) {
        signed char* S8 = (signed char*)d_ws;
        signed char* D8 = (signed char*)d_ws + s8_bytes;
        const int nS16blocks = (M * N_IN / 16) / 256;         // 8000
        prep<<<nS16blocks + N_OUT, 256, 0, stream>>>(S, S8, W, D8, nS16blocks);
        const size_t lds_bytes = (size_t)2 * BUFSZ;           // 40960
        gemm_i8<<<(M / BM) * (N_OUT / BN), 256, lds_bytes, stream>>>(S8, D8, out, M);
        lif_scan3<<<(B * N_OUT) / 64, 64, 0, stream>>>(out, T);
    } else if (ws_size >= (size_t)N_IN * N_OUT * sizeof(float) && (M % 4) == 0) {
        float* WT = (float*)d_ws;
        dim3 tg(N_IN / 32, N_OUT / 32);
        transpose_w<<<tg, 256, 0, stream>>>(W, WT);
        gather_rows<<<M / 4, 256, 0, stream>>>(S, WT, out, M);
        lif_scan3<<<(B * N_OUT) / 64, 64, 0, stream>>>(out, T);
    }
}

// Round 18
// 126.616 us; speedup vs baseline: 1.0174x; 1.0174x over previous
//
#include <hip/hip_runtime.h>

// LIF spiking net forward, v18 == v15 (best measured: 126.7 us) — 3-digit
// fixed-point i8 MFMA GEMM, X/Y-pipelined fragment reads, one barrier/K-tile.
//   W -> 3 signed base-256 digits of round(W * 2^26)  (|top digit| <= ~97)
//   S (binary fp32) -> i8
//   I = sum_d 2^(8d) * (S_i8 @ digit_d^T)  in int64, one fp32 round.
//   Quantization error ~5e-8 RMS (proven flip-free: absmax 0.0).
// Final structure: prep (S->i8 + W->digits, HBM-floor ~26us) -> gemm_i8
// (LDS-feed-bound ~62us; occupancy ladder v15/v16/v17 all +/-2%) -> lif_scan3
// (~28us, 1 wave/CU, 16384 serial chains). v16/v17 falsified the occupancy
// hypothesis; v15 is the plateau of this decomposition.

#define N_IN   1024
#define N_OUT  512
#define DECAY_F 0.95122942450071400910f
#define SCALE     67108864.0               // 2^26
#define SCALE_INV 1.4901161193847656e-08f  // 2^-26

typedef int  v4i  __attribute__((ext_vector_type(4)));
typedef int  v16i __attribute__((ext_vector_type(16)));

typedef __attribute__((address_space(1))) const void gv_t;
typedef __attribute__((address_space(3))) void lv_t;
__device__ __forceinline__ void gl16(const signed char* g, signed char* l) {
    __builtin_amdgcn_global_load_lds((gv_t*)g, (lv_t*)l, 16, 0, 0);
}

// ---------------- kernel 1: fused prep: S->i8  |  W->3 digit planes --------
__global__ __launch_bounds__(256) void prep(const float* __restrict__ S,
                                            signed char* __restrict__ S8,
                                            const float* __restrict__ W,
                                            signed char* __restrict__ D8,
                                            int nS16blocks) {
    if ((int)blockIdx.x < nS16blocks) {
        const int g = blockIdx.x * 256 + threadIdx.x;
        const float4* p = reinterpret_cast<const float4*>(S) + (size_t)g * 4;
        union { signed char c[16]; int4 v; } u;
#pragma unroll
        for (int q = 0; q < 4; ++q) {
            const float4 v = p[q];
            u.c[q * 4 + 0] = (signed char)(v.x != 0.f);
            u.c[q * 4 + 1] = (signed char)(v.y != 0.f);
            u.c[q * 4 + 2] = (signed char)(v.z != 0.f);
            u.c[q * 4 + 3] = (signed char)(v.w != 0.f);
        }
        reinterpret_cast<int4*>(S8)[g] = u.v;
    } else {
        const int n  = blockIdx.x - nS16blocks;   // 0..511
        const int k0 = threadIdx.x * 4;
        const float4 wv = *reinterpret_cast<const float4*>(W + (size_t)n * N_IN + k0);
        const float ww[4] = {wv.x, wv.y, wv.z, wv.w};
        int pk[3] = {0, 0, 0};
#pragma unroll
        for (int j = 0; j < 4; ++j) {
            long long wi = (long long)rint((double)ww[j] * SCALE);
            const int d0 = (int)((wi + 128) & 255) - 128; wi = (wi - d0) >> 8;
            const int d1 = (int)((wi + 128) & 255) - 128; wi = (wi - d1) >> 8;
            const int d2 = (int)wi;           // |d2| <= ~97
            pk[0] |= (d0 & 255) << (8 * j);
            pk[1] |= (d1 & 255) << (8 * j);
            pk[2] |= (d2 & 255) << (8 * j);
        }
#pragma unroll
        for (int d = 0; d < 3; ++d)
            *reinterpret_cast<int*>(D8 + (size_t)(d * N_OUT + n) * N_IN + k0) = pk[d];
    }
}

// ---------------- kernel 2: i8 MFMA GEMM, 3 digits, 1 barrier / K-tile -----
#define BM 256
#define BN 64
#define BK 64
#define ATILE (BM * BK)            // 16384 B
#define BTILE (192 * BK)           // 12288 B (3 digits x 64 rows)
#define BUFSZ (ATILE + BTILE)      // 28672 B; 3 buffers = 86016 B

#define BARRIER __builtin_amdgcn_s_barrier()
#define SB0 __builtin_amdgcn_sched_barrier(0)
#define LGKM(n) do { asm volatile("s_waitcnt lgkmcnt(" #n ")" ::: "memory"); SB0; } while (0)
#define VMCNT_(n) asm volatile("s_waitcnt vmcnt(" #n ")" ::: "memory")
#define VMC do { if (w < 4) VMCNT_(4); else VMCNT_(3); } while (0)
#define LDV(off) (*reinterpret_cast<const v4i*>(lds + (off)))
#define MFMA_I8 __builtin_amdgcn_mfma_i32_32x32x32_i8

__global__ __launch_bounds__(512, 2) void gemm_i8(
        const signed char* __restrict__ S8,   // (M, 1024)
        const signed char* __restrict__ D8,   // (1536, 1024), row = d*512+n
        float* __restrict__ I, int M) {       // (M, 512)
    extern __shared__ signed char lds[];

    const int tid  = threadIdx.x;
    const int lane = tid & 63;
    const int w    = tid >> 6;          // 0..7
    const int wwm  = w >> 1;            // 0..3 -> M offset *64
    const int wwn  = w & 1;             // 0..1 -> N offset *32

    // XCD-aware bijective swizzle (grid 1000 = 8*125)
    const int nx  = M / BM;
    const int u   = (blockIdx.x & 7) * nx + (blockIdx.x >> 3);
    const int bm  = u >> 3;
    const int bn  = u & 7;
    const int m0 = bm * BM;
    const int n0 = bn * BN;

    // staging geometry: linear LDS [row][64], source column pre-swizzled so
    // reads use col ^ ((row>>1)&3)<<4.
    const int lrow  = lane >> 2;             // 0..15
    const int sslot = (lane & 3) << 4;
    const int swzs  = ((lrow >> 1) & 3) << 4;
    const int scola = sslot ^ swzs;

    const signed char* aSrc0 = S8 + (size_t)(m0 + w * 16 + lrow) * N_IN + scola;
    const signed char* aSrc1 = aSrc0 + (size_t)128 * N_IN;
    // B LDS row = d*64 + j ; global row = d*512 + n0 + j
    const signed char* bSrc0 = D8 + (size_t)((w >> 2) * N_OUT + n0 + (w & 3) * 16 + lrow) * N_IN + scola;
    const signed char* bSrc1 = bSrc0 + (size_t)2 * N_OUT * N_IN;   // d=2 (w<4 only)

    const int aDst0 = (w * 16) * 64;
    const int aDst1 = aDst0 + 128 * 64;
    const int bDst0 = ATILE + (w * 16) * 64;          // rows 0..127 (d0,d1)
    const int bDst1 = bDst0 + 128 * 64;               // rows 128..191 (d2), w<4

    v16i acc[2][3];
#pragma unroll
    for (int mf = 0; mf < 2; ++mf)
#pragma unroll
        for (int d = 0; d < 3; ++d)
#pragma unroll
            for (int i = 0; i < 16; ++i) acc[mf][d][i] = 0;

    const int fr = lane & 31;
    const int kh = (lane >> 5) * 16;
    const int swzr = ((fr >> 1) & 3) << 4;
    const int kx0 = kh ^ swzr;                // ksub0 byte offset (swizzled)
    const int kx1 = (32 + kh) ^ swzr;         // ksub1
    const int ra0 = (wwm * 64 + fr) * 64;
    const int ra1 = (wwm * 64 + 32 + fr) * 64;
    const int rb0 = (0 * 64 + wwn * 32 + fr) * 64;
    const int rb1 = (1 * 64 + wwn * 32 + fr) * 64;
    const int rb2 = (2 * 64 + wwn * 32 + fr) * 64;

// one K-tile: issue ksub0 reads (X), ksub1 reads (Y) pinned in order;
// lgkmcnt(5) -> MFMA X while Y in flight; lgkmcnt(0) -> MFMA Y;
// gl16 staging interleaved; counted vmcnt + single raw barrier at tile end.
#define TILE_STEP(CUR, STG, KT, DOSTAGE)                                          \
    {                                                                             \
        const int base = (CUR) * BUFSZ;                                           \
        v4i xa0, xa1, xb0, xb1, xb2;                                              \
        v4i ya0, ya1, yb0, yb1, yb2;                                              \
        xa0 = LDV(base + ra0 + kx0);                                              \
        xa1 = LDV(base + ra1 + kx0);                                              \
        xb0 = LDV(base + ATILE + rb0 + kx0);                                      \
        xb1 = LDV(base + ATILE + rb1 + kx0);                                      \
        xb2 = LDV(base + ATILE + rb2 + kx0);                                      \
        SB0;                                                                      \
        ya0 = LDV(base + ra0 + kx1);                                              \
        ya1 = LDV(base + ra1 + kx1);                                              \
        yb0 = LDV(base + ATILE + rb0 + kx1);                                      \
        yb1 = LDV(base + ATILE + rb1 + kx1);                                      \
        yb2 = LDV(base + ATILE + rb2 + kx1);                                      \
        SB0;                                                                      \
        LGKM(5);                                                                  \
        if (DOSTAGE) {                                                            \
            gl16(aSrc0 + (KT + 2) * BK, lds + (STG) * BUFSZ + aDst0);             \
            gl16(aSrc1 + (KT + 2) * BK, lds + (STG) * BUFSZ + aDst1);             \
        }                                                                         \
        __builtin_amdgcn_s_setprio(1);                                            \
        acc[0][0] = MFMA_I8(xa0, xb0, acc[0][0], 0, 0, 0);                        \
        acc[1][0] = MFMA_I8(xa1, xb0, acc[1][0], 0, 0, 0);                        \
        acc[0][1] = MFMA_I8(xa0, xb1, acc[0][1], 0, 0, 0);                        \
        acc[1][1] = MFMA_I8(xa1, xb1, acc[1][1], 0, 0, 0);                        \
        acc[0][2] = MFMA_I8(xa0, xb2, acc[0][2], 0, 0, 0);                        \
        acc[1][2] = MFMA_I8(xa1, xb2, acc[1][2], 0, 0, 0);                        \
        __builtin_amdgcn_s_setprio(0);                                            \
        if (DOSTAGE) {                                                            \
            gl16(bSrc0 + (KT + 2) * BK, lds + (STG) * BUFSZ + bDst0);             \
            if (w < 4) gl16(bSrc1 + (KT + 2) * BK, lds + (STG) * BUFSZ + bDst1);  \
        }                                                                         \
        LGKM(0);                                                                  \
        __builtin_amdgcn_s_setprio(1);                                            \
        acc[0][0] = MFMA_I8(ya0, yb0, acc[0][0], 0, 0, 0);                        \
        acc[1][0] = MFMA_I8(ya1, yb0, acc[1][0], 0, 0, 0);                        \
        acc[0][1] = MFMA_I8(ya0, yb1, acc[0][1], 0, 0, 0);                        \
        acc[1][1] = MFMA_I8(ya1, yb1, acc[1][1], 0, 0, 0);                        \
        acc[0][2] = MFMA_I8(ya0, yb2, acc[0][2], 0, 0, 0);                        \
        acc[1][2] = MFMA_I8(ya1, yb2, acc[1][2], 0, 0, 0);                        \
        __builtin_amdgcn_s_setprio(0);                                            \
        if (DOSTAGE) { VMC; } else { VMCNT_(0); }                                 \
        BARRIER;                                                                  \
    }

    // prologue: tiles 0,1 staged into buf0,buf1; drain tile0's loads
    gl16(aSrc0, lds + aDst0);
    gl16(aSrc1, lds + aDst1);
    gl16(bSrc0, lds + bDst0);
    if (w < 4) gl16(bSrc1, lds + bDst1);
    gl16(aSrc0 + BK, lds + BUFSZ + aDst0);
    gl16(aSrc1 + BK, lds + BUFSZ + aDst1);
    gl16(bSrc0 + BK, lds + BUFSZ + bDst0);
    if (w < 4) gl16(bSrc1 + BK, lds + BUFSZ + bDst1);
    VMC;
    BARRIER;

    TILE_STEP(0, 2, 0,  1)
    TILE_STEP(1, 0, 1,  1)
    TILE_STEP(2, 1, 2,  1)
    TILE_STEP(0, 2, 3,  1)
    TILE_STEP(1, 0, 4,  1)
    TILE_STEP(2, 1, 5,  1)
    TILE_STEP(0, 2, 6,  1)
    TILE_STEP(1, 0, 7,  1)
    TILE_STEP(2, 1, 8,  1)
    TILE_STEP(0, 2, 9,  1)
    TILE_STEP(1, 0, 10, 1)
    TILE_STEP(2, 1, 11, 1)
    TILE_STEP(0, 2, 12, 1)
    TILE_STEP(1, 0, 13, 1)
    TILE_STEP(2, 1, 14, 0)
    TILE_STEP(0, 0, 15, 0)

    // epilogue: combine 3 digits in int64, one fp32 rounding
    const int col = fr;
    const int rb_ = (lane >> 5) * 4;
#pragma unroll
    for (int mf = 0; mf < 2; ++mf) {
#pragma unroll
        for (int reg = 0; reg < 16; ++reg) {
            const int row = (reg & 3) + 8 * (reg >> 2) + rb_;
            const long long v =
                ((long long)acc[mf][2][reg] << 16) +
                ((long long)acc[mf][1][reg] << 8) + (long long)acc[mf][0][reg];
            I[(size_t)(m0 + wwm * 64 + mf * 32 + row) * N_OUT + n0 + wwn * 32 + col] =
                (float)v * SCALE_INV;
        }
    }
}
#undef TILE_STEP

// ---------------- kernel 3: LIF scan, 1 wave/CU, deep prefetch ----------------
#define UT 50
__global__ __launch_bounds__(64) void lif_scan3(float* __restrict__ IO, int T) {
    const int idx = blockIdx.x * 64 + threadIdx.x;   // chain id, 16384 total
    const int b = idx >> 9, o = idx & (N_OUT - 1);
    float* p = IO + (size_t)b * T * N_OUT + o;
    float ca[UT], cb[UT];
    float v = 0.f;
#pragma unroll
    for (int j = 0; j < UT; ++j) ca[j] = p[(size_t)j * N_OUT];
#pragma unroll 1
    for (int t0 = 0; t0 < T; t0 += 2 * UT) {
        if (t0 + UT < T) {
#pragma unroll
            for (int j = 0; j < UT; ++j) cb[j] = p[(size_t)(t0 + UT + j) * N_OUT];
        }
#pragma unroll
        for (int j = 0; j < UT; ++j) {
            v = v * DECAY_F + ca[j];
            float s = (v > 1.0f) ? 1.0f : 0.f;
            v *= (1.f - s);
            ca[j] = s;
        }
#pragma unroll
        for (int j = 0; j < UT; ++j) p[(size_t)(t0 + j) * N_OUT] = ca[j];
        if (t0 + UT >= T) break;
        if (t0 + 2 * UT < T) {
#pragma unroll
            for (int j = 0; j < UT; ++j) ca[j] = p[(size_t)(t0 + 2 * UT + j) * N_OUT];
        }
#pragma unroll
        for (int j = 0; j < UT; ++j) {
            v = v * DECAY_F + cb[j];
            float s = (v > 1.0f) ? 1.0f : 0.f;
            v *= (1.f - s);
            cb[j] = s;
        }
#pragma unroll
        for (int j = 0; j < UT; ++j) p[(size_t)(t0 + UT + j) * N_OUT] = cb[j];
    }
}

// ---------------- fallback: v3 gather path ----------------
__global__ __launch_bounds__(256) void transpose_w(const float* __restrict__ W,
                                                   float* __restrict__ WT) {
    __shared__ float t[32][33];
    const int k0 = blockIdx.x * 32;
    const int n0 = blockIdx.y * 32;
    const int lx = threadIdx.x & 31;
    const int ly = threadIdx.x >> 5;
#pragma unroll
    for (int r = ly; r < 32; r += 8)
        t[r][lx] = W[(size_t)(n0 + r) * N_IN + k0 + lx];
    __syncthreads();
#pragma unroll
    for (int r = ly; r < 32; r += 8)
        WT[(size_t)(k0 + r) * N_OUT + n0 + lx] = t[lx][r];
}

__global__ __launch_bounds__(256) void gather_rows(
        const float* __restrict__ S, const float* __restrict__ WT,
        float* __restrict__ I, int M) {
    const int wid  = blockIdx.x * 4 + (threadIdx.x >> 6);
    const int lane = threadIdx.x & 63;
    if (wid >= M) return;
    const float* srow = S + (size_t)wid * N_IN;
    float4 a0 = {0.f, 0.f, 0.f, 0.f};
    float4 a1 = {0.f, 0.f, 0.f, 0.f};
    float sv[16];
#pragma unroll
    for (int g = 0; g < 16; ++g) sv[g] = srow[g * 64 + lane];
#pragma unroll
    for (int g = 0; g < 16; ++g) {
        unsigned long long m = __ballot(sv[g] != 0.0f);
        while (m) {
            const int bb = __builtin_ctzll(m);
            m &= m - 1;
            const int k = g * 64 + bb;
            const float* wp = WT + (size_t)k * N_OUT + lane * 4;
            const float4 w0 = *reinterpret_cast<const float4*>(wp);
            const float4 w1 = *reinterpret_cast<const float4*>(wp + 256);
            a0.x += w0.x; a0.y += w0.y; a0.z += w0.z; a0.w += w0.w;
            a1.x += w1.x; a1.y += w1.y; a1.z += w1.z; a1.w += w1.w;
        }
    }
    float* op = I + (size_t)wid * N_OUT + lane * 4;
    *reinterpret_cast<float4*>(op) = a0;
    *reinterpret_cast<float4*>(op + 256) = a1;
}

extern "C" void kernel_launch(void* const* d_in, const int* in_sizes, int n_in,
                              void* d_out, int out_size, void* d_ws, size_t ws_size,
                              hipStream_t stream) {
    const float* S = (const float*)d_in[0];   // (B, T, n_in) binary spikes, fp32
    const float* W = (const float*)d_in[1];   // (n_out, n_in), fp32
    float* out = (float*)d_out;               // (B, T, n_out), fp32

    const int K = N_IN;
    const int M = in_sizes[0] / K;            // 32000
    const int B = 32;
    const int T = M / B;                      // 1000

    const size_t s8_bytes = (size_t)M * N_IN;                 // 32.77 MB
    const size_t d8_bytes = (size_t)3 * N_OUT * N_IN;         // 1.5 MB
    const size_t need = s8_bytes + d8_bytes;

    if (ws_size >= need && (M % BM) == 0 && ((M / BM) * (N_OUT / BN)) % 8 == 0) {
        signed char* S8 = (signed char*)d_ws;
        signed char* D8 = (signed char*)d_ws + s8_bytes;
        const int nS16blocks = (M * N_IN / 16) / 256;         // 8000
        prep<<<nS16blocks + N_OUT, 256, 0, stream>>>(S, S8, W, D8, nS16blocks);
        const size_t lds_bytes = (size_t)3 * BUFSZ;           // 86016
        gemm_i8<<<(M / BM) * (N_OUT / BN), 512, lds_bytes, stream>>>(S8, D8, out, M);
        lif_scan3<<<(B * N_OUT) / 64, 64, 0, stream>>>(out, T);
    } else if (ws_size >= (size_t)N_IN * N_OUT * sizeof(float) && (M % 4) == 0) {
        float* WT = (float*)d_ws;
        dim3 tg(N_IN / 32, N_OUT / 32);
        transpose_w<<<tg, 256, 0, stream>>>(W, WT);
        gather_rows<<<M / 4, 256, 0, stream>>>(S, WT, out, M);
        lif_scan3<<<(B * N_OUT) / 64, 64, 0, stream>>>(out, T);
    }
}